// Round 1
// baseline (37262.766 us; speedup 1.0000x reference)
//
#include <hip/hip_runtime.h>
#include <hip/hip_bf16.h>
#include <math.h>

#define TT 4218
#define BB 2
#define DM 768
#define DI 1536
#define DS 16
#define DTR 48
#define LC 64
#define NCHUNK 66
#define ROWS (BB*TT)   // 8436
#define NLAYER 24

__device__ __forceinline__ float silu_f(float x) { return x / (1.0f + __expf(-x)); }
__device__ __forceinline__ float softplus_f(float x) {
  return (x > 15.0f) ? x : log1pf(__expf(x));
}

// ---------------- downsample conv: x (B,1,135000) -> h (B,T,768) ----------------
__global__ __launch_bounds__(256)
void k_conv_ds(const float* __restrict__ x, const float* __restrict__ cw,
               const float* __restrict__ cb, float* __restrict__ h) {
  int bt = blockIdx.x;               // 0..ROWS-1
  int b = bt / TT, t = bt % TT;
  __shared__ float xs[32];
  int tid = threadIdx.x;
  if (tid < 32) xs[tid] = x[(size_t)b*135000 + (size_t)t*32 + tid];
  __syncthreads();
  for (int d = tid; d < DM; d += 256) {
    float s = cb[d];
    const float* w = cw + d*32;
    #pragma unroll
    for (int k = 0; k < 32; ++k) s = fmaf(xs[k], w[k], s);
    h[(size_t)bt*DM + d] = s;
  }
}

// ---------------- RMSNorm over last dim (768) ----------------
__global__ __launch_bounds__(256)
void k_rmsnorm(const float* __restrict__ in, const float* __restrict__ w,
               float* __restrict__ out) {
  int row = blockIdx.x, tid = threadIdx.x;
  const float* xp = in + (size_t)row*DM;
  float v0 = xp[tid], v1 = xp[tid+256], v2 = xp[tid+512];
  float ss = v0*v0 + v1*v1 + v2*v2;
  #pragma unroll
  for (int off = 32; off > 0; off >>= 1) ss += __shfl_down(ss, off, 64);
  __shared__ float sred[4];
  if ((tid & 63) == 0) sred[tid >> 6] = ss;
  __syncthreads();
  float tot = sred[0] + sred[1] + sred[2] + sred[3];
  float sc = rsqrtf(tot * (1.0f/DM) + 1e-5f);
  float* op = out + (size_t)row*DM;
  op[tid]     = v0*sc*w[tid];
  op[tid+256] = v1*sc*w[tid+256];
  op[tid+512] = v2*sc*w[tid+512];
}

// ---------------- fp32 GEMM: C[M,N] = A[M,K] * W[N,K]^T ----------------
// 128x128 tile, BK=16, 8x8 per thread. ACT: 0 none, 1 softplus(x+bias).
// SPLIT: cols >=1536 go to C1 (col-1536). ACCUM: C += result.
template<int ACT, bool ACCUM, bool SPLIT>
__global__ __launch_bounds__(256)
void k_gemm(const float* __restrict__ A, int lda,
            const float* __restrict__ W,
            const float* __restrict__ bias,
            float* __restrict__ C0, float* __restrict__ C1,
            int ldc, int M, int N, int K) {
  __shared__ float As[16][132];
  __shared__ float Ws[16][132];
  int tid = threadIdx.x;
  int m0 = blockIdx.x * 128, n0 = blockIdx.y * 128;
  int tx = tid & 15, ty = tid >> 4;
  float acc[8][8] = {};
  for (int k0 = 0; k0 < K; k0 += 16) {
    #pragma unroll
    for (int l = 0; l < 2; ++l) {
      int fl = tid + l*256;
      int r = fl >> 2, c4 = (fl & 3) * 4;
      float4 av = make_float4(0.f,0.f,0.f,0.f);
      if (m0 + r < M) av = *(const float4*)(A + (size_t)(m0+r)*lda + k0 + c4);
      As[c4+0][r] = av.x; As[c4+1][r] = av.y; As[c4+2][r] = av.z; As[c4+3][r] = av.w;
      float4 wv = make_float4(0.f,0.f,0.f,0.f);
      if (n0 + r < N) wv = *(const float4*)(W + (size_t)(n0+r)*K + k0 + c4);
      Ws[c4+0][r] = wv.x; Ws[c4+1][r] = wv.y; Ws[c4+2][r] = wv.z; Ws[c4+3][r] = wv.w;
    }
    __syncthreads();
    #pragma unroll
    for (int k = 0; k < 16; ++k) {
      float a[8], bb[8];
      #pragma unroll
      for (int i = 0; i < 8; ++i) a[i] = As[k][ty*8+i];
      #pragma unroll
      for (int j = 0; j < 8; ++j) bb[j] = Ws[k][tx*8+j];
      #pragma unroll
      for (int i = 0; i < 8; ++i)
        #pragma unroll
        for (int j = 0; j < 8; ++j)
          acc[i][j] = fmaf(a[i], bb[j], acc[i][j]);
    }
    __syncthreads();
  }
  float* Cb = C0;
  int ncol0 = n0;
  if (SPLIT && n0 >= DI) { Cb = C1; ncol0 = n0 - DI; }
  #pragma unroll
  for (int i = 0; i < 8; ++i) {
    int r = m0 + ty*8 + i;
    if (r >= M) continue;
    #pragma unroll
    for (int j = 0; j < 8; ++j) {
      int c = n0 + tx*8 + j;
      if (c >= N) continue;
      float v = acc[i][j];
      if (ACT == 1) v = softplus_f(v + bias[c]);
      size_t off = (size_t)r*ldc + (ncol0 + tx*8 + j);
      if (ACCUM) Cb[off] += v; else Cb[off] = v;
    }
  }
}

// ---------------- small-N GEMM for x_proj: C[M,80] = A[M,1536] * W[80,1536]^T ----
__global__ __launch_bounds__(256)
void k_gemm_n80(const float* __restrict__ A, const float* __restrict__ W,
                float* __restrict__ C, int M) {
  __shared__ float As[32][33];
  __shared__ float Ws[80][33];
  int tid = threadIdx.x;
  int m0 = blockIdx.x * 32;
  int m = tid & 31, g = tid >> 5;   // g: 0..7 -> 10 cols each
  float acc[10] = {};
  for (int k0 = 0; k0 < DI; k0 += 32) {
    #pragma unroll
    for (int l = 0; l < 4; ++l) {
      int idx = tid + l*256;
      int r = idx >> 5, c = idx & 31;
      As[r][c] = (m0 + r < M) ? A[(size_t)(m0+r)*DI + k0 + c] : 0.0f;
    }
    #pragma unroll
    for (int l = 0; l < 10; ++l) {
      int idx = tid + l*256;
      int r = idx >> 5, c = idx & 31;
      Ws[r][c] = W[(size_t)r*DI + k0 + c];
    }
    __syncthreads();
    #pragma unroll
    for (int c = 0; c < 32; ++c) {
      float a = As[m][c];
      #pragma unroll
      for (int j = 0; j < 10; ++j)
        acc[j] = fmaf(a, Ws[g*10+j][c], acc[j]);
    }
    __syncthreads();
  }
  int row = m0 + m;
  if (row < M) {
    #pragma unroll
    for (int j = 0; j < 10; ++j) C[(size_t)row*80 + g*10 + j] = acc[j];
  }
}

// ---------------- causal depthwise conv (k=4) + silu ----------------
__global__ __launch_bounds__(256)
void k_dwconv(const float* __restrict__ U0, const float* __restrict__ cw,
              const float* __restrict__ cb, float* __restrict__ u) {
  size_t i = (size_t)blockIdx.x*256 + threadIdx.x;
  if (i >= (size_t)ROWS*DI) return;
  int d = (int)(i % DI);
  long bt = (long)(i / DI);
  int t = (int)(bt % TT);
  float s = cb[d];
  #pragma unroll
  for (int k = 0; k < 4; ++k) {
    int tt = t - 3 + k;
    if (tt >= 0) s = fmaf(U0[(size_t)(bt - 3 + k)*DI + d], cw[d*4 + k], s);
  }
  u[i] = silu_f(s);
}

// ---------------- selective scan, 3-pass chunked linear recurrence ----------------
// pass1: per (b,d,chunk): P = prod exp(dl*A), H0 = chunk-end state with h_start=0
__global__ __launch_bounds__(256)
void k_scan1(const float* __restrict__ delta, const float* __restrict__ u,
             const float* __restrict__ proj, const float* __restrict__ A_log,
             float* __restrict__ P, float* __restrict__ H) {
  int c = blockIdx.x, b = blockIdx.z;
  int d = blockIdx.y * 256 + threadIdx.x;
  float A[DS];
  #pragma unroll
  for (int s = 0; s < DS; ++s) A[s] = -__expf(A_log[d*DS + s]);
  float h[DS] = {};
  float Pp[DS];
  #pragma unroll
  for (int s = 0; s < DS; ++s) Pp[s] = 1.0f;
  int t0 = c * LC, t1 = min(t0 + LC, TT);
  for (int t = t0; t < t1; ++t) {
    size_t bt = (size_t)b*TT + t;
    float dl = delta[bt*DI + d];
    float du = dl * u[bt*DI + d];
    const float* pbm = proj + bt*80 + DTR;
    #pragma unroll
    for (int s = 0; s < DS; ++s) {
      float e = __expf(dl * A[s]);
      Pp[s] *= e;
      h[s] = fmaf(e, h[s], du * pbm[s]);
    }
  }
  size_t o = (((size_t)c*BB + b)*DI + d)*DS;
  #pragma unroll
  for (int s = 0; s < DS; ++s) { P[o+s] = Pp[s]; H[o+s] = h[s]; }
}

// pass2: sequential over chunks; rewrite H[c] := state at START of chunk c
__global__ __launch_bounds__(256)
void k_scan2(float* __restrict__ P, float* __restrict__ H) {
  int i = blockIdx.x*256 + threadIdx.x;   // < BB*DI*DS
  const int CH = BB*DI*DS;
  float carry = 0.0f;
  for (int c = 0; c < NCHUNK; ++c) {
    size_t o = (size_t)c*CH + i;
    float p = P[o], h0 = H[o];
    H[o] = carry;
    carry = fmaf(p, carry, h0);
  }
}

// pass3: replay with correct start state; y = (scan_out + u*D) * silu(z)
__global__ __launch_bounds__(256)
void k_scan3(const float* __restrict__ delta, const float* __restrict__ u,
             const float* __restrict__ z, const float* __restrict__ proj,
             const float* __restrict__ A_log, const float* __restrict__ Dskip,
             const float* __restrict__ H, float* __restrict__ y) {
  int c = blockIdx.x, b = blockIdx.z;
  int d = blockIdx.y * 256 + threadIdx.x;
  float A[DS];
  #pragma unroll
  for (int s = 0; s < DS; ++s) A[s] = -__expf(A_log[d*DS + s]);
  float h[DS];
  size_t o = (((size_t)c*BB + b)*DI + d)*DS;
  #pragma unroll
  for (int s = 0; s < DS; ++s) h[s] = H[o+s];
  float Dd = Dskip[d];
  int t0 = c * LC, t1 = min(t0 + LC, TT);
  for (int t = t0; t < t1; ++t) {
    size_t bt = (size_t)b*TT + t;
    float dl = delta[bt*DI + d];
    float uu = u[bt*DI + d];
    float du = dl * uu;
    const float* pbm = proj + bt*80 + DTR;
    const float* pcm = pbm + DS;
    float yt = 0.0f;
    #pragma unroll
    for (int s = 0; s < DS; ++s) {
      float e = __expf(dl * A[s]);
      h[s] = fmaf(e, h[s], du * pbm[s]);
      yt = fmaf(h[s], pcm[s], yt);
    }
    float zz = z[bt*DI + d];
    y[bt*DI + d] = (yt + uu*Dd) * silu_f(zz);
  }
}

// ---------------- mean-pool partials over T ----------------
__global__ __launch_bounds__(256)
void k_poolpart(const float* __restrict__ hn, float* __restrict__ pp) {
  int seg = blockIdx.x, b = blockIdx.z;
  int d = blockIdx.y*256 + threadIdx.x;
  int t0 = seg*132, t1 = min(t0 + 132, TT);
  float s = 0.0f;
  for (int t = t0; t < t1; ++t) s += hn[((size_t)b*TT + t)*DM + d];
  pp[((size_t)b*32 + seg)*DM + d] = s;
}

// ---------------- final head: pool-sum, proj to 64, LayerNorm ----------------
__global__ __launch_bounds__(256)
void k_head(const float* __restrict__ pp, const float* __restrict__ pw,
            const float* __restrict__ pb, const float* __restrict__ lnw,
            const float* __restrict__ lnb, float* __restrict__ out) {
  int b = blockIdx.x, tid = threadIdx.x;
  __shared__ float pooled[DM];
  for (int d = tid; d < DM; d += 256) {
    float s = 0.0f;
    for (int seg = 0; seg < 32; ++seg) s += pp[((size_t)b*32 + seg)*DM + d];
    pooled[d] = s * (1.0f/(float)TT);
  }
  __syncthreads();
  __shared__ float zed[64];
  if (tid < 64) {
    float s = pb[tid];
    const float* w = pw + (size_t)tid*DM;
    for (int d = 0; d < DM; ++d) s = fmaf(pooled[d], w[d], s);
    zed[tid] = s;
  }
  __syncthreads();
  __shared__ float mv[2];
  if (tid == 0) {
    float mu = 0.0f;
    for (int l = 0; l < 64; ++l) mu += zed[l];
    mu *= (1.0f/64.0f);
    float var = 0.0f;
    for (int l = 0; l < 64; ++l) { float dd = zed[l]-mu; var += dd*dd; }
    var *= (1.0f/64.0f);
    mv[0] = mu; mv[1] = rsqrtf(var + 1e-5f);
  }
  __syncthreads();
  if (tid < 64) out[b*64 + tid] = (zed[tid]-mv[0])*mv[1]*lnw[tid] + lnb[tid];
}

extern "C" void kernel_launch(void* const* d_in, const int* in_sizes, int n_in,
                              void* d_out, int out_size, void* d_ws, size_t ws_size,
                              hipStream_t stream) {
  (void)in_sizes; (void)n_in; (void)out_size; (void)ws_size;
  const float* x    = (const float*)d_in[0];
  const float* cw   = (const float*)d_in[1];
  const float* cb   = (const float*)d_in[2];
  const float* nw   = (const float*)d_in[3];
  const float* inw  = (const float*)d_in[4];
  const float* c1w  = (const float*)d_in[5];
  const float* c1b  = (const float*)d_in[6];
  const float* xpw  = (const float*)d_in[7];
  const float* dtw  = (const float*)d_in[8];
  const float* dtb  = (const float*)d_in[9];
  const float* alog = (const float*)d_in[10];
  const float* dsk  = (const float*)d_in[11];
  const float* outw = (const float*)d_in[12];
  const float* nfw  = (const float*)d_in[13];
  const float* pw   = (const float*)d_in[14];
  const float* pb   = (const float*)d_in[15];
  const float* lnw  = (const float*)d_in[16];
  const float* lnb  = (const float*)d_in[17];

  float* ws = (float*)d_ws;
  size_t o = 0;
  float* f_h  = ws + o; o += (size_t)ROWS*DM;
  float* f_hn = ws + o; o += (size_t)ROWS*DM;
  float* f_u0 = ws + o; o += (size_t)ROWS*DI;   // u_raw, later reused as y
  float* f_z  = ws + o; o += (size_t)ROWS*DI;
  float* f_u  = ws + o; o += (size_t)ROWS*DI;
  float* f_pr = ws + o; o += (size_t)ROWS*80;
  float* f_dl = ws + o; o += (size_t)ROWS*DI;
  float* f_P  = ws + o; o += (size_t)NCHUNK*BB*DI*DS;
  float* f_H  = ws + o; o += (size_t)NCHUNK*BB*DI*DS;
  float* f_pp = ws + o; o += (size_t)BB*32*DM;

  k_conv_ds<<<ROWS, 256, 0, stream>>>(x, cw, cb, f_h);

  for (int lay = 0; lay < NLAYER; ++lay) {
    k_rmsnorm<<<ROWS, 256, 0, stream>>>(f_h, nw + (size_t)lay*DM, f_hn);
    k_gemm<0,false,true><<<dim3(66,24), 256, 0, stream>>>(
        f_hn, DM, inw + (size_t)lay*2*DI*DM, nullptr,
        f_u0, f_z, DI, ROWS, 2*DI, DM);
    k_dwconv<<<(ROWS*DI+255)/256, 256, 0, stream>>>(
        f_u0, c1w + (size_t)lay*DI*4, c1b + (size_t)lay*DI, f_u);
    k_gemm_n80<<<264, 256, 0, stream>>>(f_u, xpw + (size_t)lay*80*DI, f_pr, ROWS);
    k_gemm<1,false,false><<<dim3(66,12), 256, 0, stream>>>(
        f_pr, 80, dtw + (size_t)lay*DI*DTR, dtb + (size_t)lay*DI,
        f_dl, nullptr, DI, ROWS, DI, DTR);
    k_scan1<<<dim3(NCHUNK,6,BB), 256, 0, stream>>>(
        f_dl, f_u, f_pr, alog + (size_t)lay*DI*DS, f_P, f_H);
    k_scan2<<<dim3((BB*DI*DS)/256), 256, 0, stream>>>(f_P, f_H);
    k_scan3<<<dim3(NCHUNK,6,BB), 256, 0, stream>>>(
        f_dl, f_u, f_z, f_pr, alog + (size_t)lay*DI*DS,
        dsk + (size_t)lay*DI, f_H, f_u0);
    k_gemm<0,true,false><<<dim3(66,6), 256, 0, stream>>>(
        f_u0, DI, outw + (size_t)lay*DM*DI, nullptr,
        f_h, nullptr, DM, ROWS, DM, DI);
  }

  k_rmsnorm<<<ROWS, 256, 0, stream>>>(f_h, nfw, f_hn);
  k_poolpart<<<dim3(32,3,BB), 256, 0, stream>>>(f_hn, f_pp);
  k_head<<<BB, 256, 0, stream>>>(f_pp, pw, pb, lnw, lnb, (float*)d_out);
}

// Round 2
// 14018.202 us; speedup vs baseline: 2.6582x; 2.6582x over previous
//
#include <hip/hip_runtime.h>
#include <hip/hip_bf16.h>
#include <math.h>

#define TT 4218
#define BB 2
#define DM 768
#define DI 1536
#define DS 16
#define DTR 48
#define LC 64
#define NCHUNK 66
#define ROWS (BB*TT)   // 8436
#define NLAYER 24

typedef short short8 __attribute__((ext_vector_type(8)));
typedef float f32x4 __attribute__((ext_vector_type(4)));

__device__ __forceinline__ float silu_f(float x) { return x / (1.0f + __expf(-x)); }
__device__ __forceinline__ float softplus_f(float x) {
  return (x > 15.0f) ? x : log1pf(__expf(x));
}
__device__ __forceinline__ unsigned short f2bf(float x) {  // RNE
  unsigned int u = __float_as_uint(x);
  u = (u + 0x7fffu + ((u >> 16) & 1u)) >> 16;
  return (unsigned short)u;
}
__device__ __forceinline__ float bf2f(unsigned short s) {
  return __uint_as_float(((unsigned int)s) << 16);
}

// ---------------- fp32 -> bf16 bulk convert (weights) ----------------
__global__ __launch_bounds__(256)
void k_f2bf(const float4* __restrict__ in, ushort4* __restrict__ out, int n4) {
  int i = blockIdx.x*256 + threadIdx.x;
  if (i >= n4) return;
  float4 v = in[i];
  ushort4 o;
  o.x = f2bf(v.x); o.y = f2bf(v.y); o.z = f2bf(v.z); o.w = f2bf(v.w);
  out[i] = o;
}

// ---------------- downsample conv: x (B,1,135000) -> h (B,T,768) ----------------
__global__ __launch_bounds__(256)
void k_conv_ds(const float* __restrict__ x, const float* __restrict__ cw,
               const float* __restrict__ cb, float* __restrict__ h) {
  int bt = blockIdx.x;
  int b = bt / TT, t = bt % TT;
  __shared__ float xs[32];
  int tid = threadIdx.x;
  if (tid < 32) xs[tid] = x[(size_t)b*135000 + (size_t)t*32 + tid];
  __syncthreads();
  for (int d = tid; d < DM; d += 256) {
    float s = cb[d];
    const float* w = cw + d*32;
    #pragma unroll
    for (int k = 0; k < 32; ++k) s = fmaf(xs[k], w[k], s);
    h[(size_t)bt*DM + d] = s;
  }
}

// ---------------- RMSNorm over last dim (768), bf16 output ----------------
__global__ __launch_bounds__(256)
void k_rmsnorm(const float* __restrict__ in, const float* __restrict__ w,
               unsigned short* __restrict__ out) {
  int row = blockIdx.x, tid = threadIdx.x;
  const float* xp = in + (size_t)row*DM;
  float v0 = xp[tid], v1 = xp[tid+256], v2 = xp[tid+512];
  float ss = v0*v0 + v1*v1 + v2*v2;
  #pragma unroll
  for (int off = 32; off > 0; off >>= 1) ss += __shfl_down(ss, off, 64);
  __shared__ float sred[4];
  if ((tid & 63) == 0) sred[tid >> 6] = ss;
  __syncthreads();
  float tot = sred[0] + sred[1] + sred[2] + sred[3];
  float sc = rsqrtf(tot * (1.0f/DM) + 1e-5f);
  unsigned short* op = out + (size_t)row*DM;
  op[tid]     = f2bf(v0*sc*w[tid]);
  op[tid+256] = f2bf(v1*sc*w[tid+256]);
  op[tid+512] = f2bf(v2*sc*w[tid+512]);
}

// ---------------- bf16 MFMA GEMM: C[M,N] = A[M,K] * W[N,K]^T ----------------
// 128x128 tile, BK=32, 4 waves of 64x64, 16x16x32 MFMA, global_load_lds staging
// with XOR-swizzled LDS (2-way bank aliasing = free).
#define GLL(g, l) __builtin_amdgcn_global_load_lds( \
    (const __attribute__((address_space(1))) void*)(g), \
    (__attribute__((address_space(3))) void*)(l), 16, 0, 0)

template<bool SPLIT, bool ACCUM>
__global__ __launch_bounds__(256)
void k_gemm_bf(const unsigned short* __restrict__ A,
               const unsigned short* __restrict__ W,
               float* __restrict__ C0, float* __restrict__ C1,
               int ldc, int M, int N, int K) {
  __shared__ unsigned short As[128*32];
  __shared__ unsigned short Ws[128*32];
  const int tid = threadIdx.x;
  const int m0 = blockIdx.x*128, n0 = blockIdx.y*128;
  const int lane = tid & 63;
  const int wave = tid >> 6;
  const int wm = (wave >> 1)*64, wn = (wave & 1)*64;

  // staging: idx = q*256+tid; row = idx>>2, s = idx&3; lane loads global seg
  // seg = s ^ ((row>>1)&3) so LDS slot (row,s) holds G[row][s^((row>>1)&3)]
  const int sA = tid & 3;
  const int r0 = tid >> 2;          // 0..63
  const int r1 = r0 + 64;           // 64..127
  const int seg0 = sA ^ ((r0 >> 1) & 3);
  const int seg1 = sA ^ ((r1 >> 1) & 3);
  const unsigned short* gA0 = A + (size_t)min(m0+r0, M-1)*K + seg0*8;
  const unsigned short* gA1 = A + (size_t)min(m0+r1, M-1)*K + seg1*8;
  const unsigned short* gW0 = W + (size_t)min(n0+r0, N-1)*K + seg0*8;
  const unsigned short* gW1 = W + (size_t)min(n0+r1, N-1)*K + seg1*8;
  unsigned short* lA0 = As + tid*8;
  unsigned short* lA1 = As + (tid+256)*8;
  unsigned short* lW0 = Ws + tid*8;
  unsigned short* lW1 = Ws + (tid+256)*8;

  f32x4 acc[4][4];
  #pragma unroll
  for (int i = 0; i < 4; ++i)
    #pragma unroll
    for (int j = 0; j < 4; ++j) acc[i][j] = (f32x4){0.f,0.f,0.f,0.f};

  // fragment read offsets: lane reads row (tile*16 + (lane&15)), kgrp = lane>>4,
  // swizzled slot = kgrp ^ ((row>>1)&3); tile base is mult of 16 so only lane matters
  const int lr = lane & 15, kg = lane >> 4;
  const int sw = (kg ^ ((lr >> 1) & 3)) * 8;
  const int aoff = (wm + lr)*32 + sw;
  const int boff = (wn + lr)*32 + sw;

  for (int k0 = 0; k0 < K; k0 += 32) {
    GLL(gA0, lA0); GLL(gA1, lA1);
    GLL(gW0, lW0); GLL(gW1, lW1);
    gA0 += 32; gA1 += 32; gW0 += 32; gW1 += 32;
    __syncthreads();
    short8 af[4], bfr[4];
    #pragma unroll
    for (int i = 0; i < 4; ++i) {
      af[i]  = *(const short8*)(As + aoff + i*512);
      bfr[i] = *(const short8*)(Ws + boff + i*512);
    }
    #pragma unroll
    for (int i = 0; i < 4; ++i)
      #pragma unroll
      for (int j = 0; j < 4; ++j)
        acc[i][j] = __builtin_amdgcn_mfma_f32_16x16x32_bf16(af[i], bfr[j], acc[i][j], 0, 0, 0);
    __syncthreads();
  }

  // epilogue: C/D layout col=lane&15, row=(lane>>4)*4+reg
  #pragma unroll
  for (int i = 0; i < 4; ++i) {
    int gr0 = m0 + wm + i*16 + (lane >> 4)*4;
    #pragma unroll
    for (int j = 0; j < 4; ++j) {
      int gc = n0 + wn + j*16 + (lane & 15);
      if (gc >= N) continue;
      float* Cb = C0; int cc = gc;
      if (SPLIT && gc >= DI) { Cb = C1; cc = gc - DI; }
      #pragma unroll
      for (int r = 0; r < 4; ++r) {
        int gr = gr0 + r;
        if (gr < M) {
          size_t off = (size_t)gr*ldc + cc;
          float v = acc[i][j][r];
          if (ACCUM) Cb[off] += v; else Cb[off] = v;
        }
      }
    }
  }
}

// ---------------- fp32 GEMM (kept for dt_proj, K=48) ----------------
template<int ACT>
__global__ __launch_bounds__(256)
void k_gemm(const float* __restrict__ A, int lda,
            const float* __restrict__ W,
            const float* __restrict__ bias,
            float* __restrict__ C0, int ldc, int M, int N, int K) {
  __shared__ float As[16][132];
  __shared__ float Ws[16][132];
  int tid = threadIdx.x;
  int m0 = blockIdx.x * 128, n0 = blockIdx.y * 128;
  int tx = tid & 15, ty = tid >> 4;
  float acc[8][8] = {};
  for (int k0 = 0; k0 < K; k0 += 16) {
    #pragma unroll
    for (int l = 0; l < 2; ++l) {
      int fl = tid + l*256;
      int r = fl >> 2, c4 = (fl & 3) * 4;
      float4 av = make_float4(0.f,0.f,0.f,0.f);
      if (m0 + r < M) av = *(const float4*)(A + (size_t)(m0+r)*lda + k0 + c4);
      As[c4+0][r] = av.x; As[c4+1][r] = av.y; As[c4+2][r] = av.z; As[c4+3][r] = av.w;
      float4 wv = make_float4(0.f,0.f,0.f,0.f);
      if (n0 + r < N) wv = *(const float4*)(W + (size_t)(n0+r)*K + k0 + c4);
      Ws[c4+0][r] = wv.x; Ws[c4+1][r] = wv.y; Ws[c4+2][r] = wv.z; Ws[c4+3][r] = wv.w;
    }
    __syncthreads();
    #pragma unroll
    for (int k = 0; k < 16; ++k) {
      float a[8], bb[8];
      #pragma unroll
      for (int i = 0; i < 8; ++i) a[i] = As[k][ty*8+i];
      #pragma unroll
      for (int j = 0; j < 8; ++j) bb[j] = Ws[k][tx*8+j];
      #pragma unroll
      for (int i = 0; i < 8; ++i)
        #pragma unroll
        for (int j = 0; j < 8; ++j)
          acc[i][j] = fmaf(a[i], bb[j], acc[i][j]);
    }
    __syncthreads();
  }
  #pragma unroll
  for (int i = 0; i < 8; ++i) {
    int r = m0 + ty*8 + i;
    if (r >= M) continue;
    #pragma unroll
    for (int j = 0; j < 8; ++j) {
      int c = n0 + tx*8 + j;
      if (c >= N) continue;
      float v = acc[i][j];
      if (ACT == 1) v = softplus_f(v + bias[c]);
      C0[(size_t)r*ldc + c] = v;
    }
  }
}

// ---------------- causal depthwise conv (k=4) + silu; fp32 + bf16 out ----------------
__global__ __launch_bounds__(256)
void k_dwconv(const float* __restrict__ U0, const float* __restrict__ cw,
              const float* __restrict__ cb, float* __restrict__ u,
              unsigned short* __restrict__ ubf) {
  size_t i = (size_t)blockIdx.x*256 + threadIdx.x;
  if (i >= (size_t)ROWS*DI) return;
  int d = (int)(i % DI);
  long bt = (long)(i / DI);
  int t = (int)(bt % TT);
  float s = cb[d];
  #pragma unroll
  for (int k = 0; k < 4; ++k) {
    int tt = t - 3 + k;
    if (tt >= 0) s = fmaf(U0[(size_t)(bt - 3 + k)*DI + d], cw[d*4 + k], s);
  }
  float v = silu_f(s);
  u[i] = v;
  ubf[i] = f2bf(v);
}

// ---------------- selective scan, 3-pass chunked linear recurrence ----------------
__global__ __launch_bounds__(256)
void k_scan1(const float* __restrict__ delta, const float* __restrict__ u,
             const float* __restrict__ proj, const float* __restrict__ A_log,
             float* __restrict__ P, float* __restrict__ H) {
  int c = blockIdx.x, b = blockIdx.z;
  int d = blockIdx.y * 256 + threadIdx.x;
  float A[DS];
  #pragma unroll
  for (int s = 0; s < DS; ++s) A[s] = -__expf(A_log[d*DS + s]);
  float h[DS] = {};
  float Pp[DS];
  #pragma unroll
  for (int s = 0; s < DS; ++s) Pp[s] = 1.0f;
  int t0 = c * LC, t1 = min(t0 + LC, TT);
  for (int t = t0; t < t1; ++t) {
    size_t bt = (size_t)b*TT + t;
    float dl = delta[bt*DI + d];
    float du = dl * u[bt*DI + d];
    const float* pbm = proj + bt*80 + DTR;
    #pragma unroll
    for (int s = 0; s < DS; ++s) {
      float e = __expf(dl * A[s]);
      Pp[s] *= e;
      h[s] = fmaf(e, h[s], du * pbm[s]);
    }
  }
  size_t o = (((size_t)c*BB + b)*DI + d)*DS;
  #pragma unroll
  for (int s = 0; s < DS; ++s) { P[o+s] = Pp[s]; H[o+s] = h[s]; }
}

__global__ __launch_bounds__(256)
void k_scan2(float* __restrict__ P, float* __restrict__ H) {
  int i = blockIdx.x*256 + threadIdx.x;
  const int CH = BB*DI*DS;
  float carry = 0.0f;
  for (int c = 0; c < NCHUNK; ++c) {
    size_t o = (size_t)c*CH + i;
    float p = P[o], h0 = H[o];
    H[o] = carry;
    carry = fmaf(p, carry, h0);
  }
}

// pass3: replay; y = (scan_out + u*D) * silu(z), bf16 output
__global__ __launch_bounds__(256)
void k_scan3(const float* __restrict__ delta, const float* __restrict__ u,
             const float* __restrict__ z, const float* __restrict__ proj,
             const float* __restrict__ A_log, const float* __restrict__ Dskip,
             const float* __restrict__ H, unsigned short* __restrict__ y) {
  int c = blockIdx.x, b = blockIdx.z;
  int d = blockIdx.y * 256 + threadIdx.x;
  float A[DS];
  #pragma unroll
  for (int s = 0; s < DS; ++s) A[s] = -__expf(A_log[d*DS + s]);
  float h[DS];
  size_t o = (((size_t)c*BB + b)*DI + d)*DS;
  #pragma unroll
  for (int s = 0; s < DS; ++s) h[s] = H[o+s];
  float Dd = Dskip[d];
  int t0 = c * LC, t1 = min(t0 + LC, TT);
  for (int t = t0; t < t1; ++t) {
    size_t bt = (size_t)b*TT + t;
    float dl = delta[bt*DI + d];
    float uu = u[bt*DI + d];
    float du = dl * uu;
    const float* pbm = proj + bt*80 + DTR;
    const float* pcm = pbm + DS;
    float yt = 0.0f;
    #pragma unroll
    for (int s = 0; s < DS; ++s) {
      float e = __expf(dl * A[s]);
      h[s] = fmaf(e, h[s], du * pbm[s]);
      yt = fmaf(h[s], pcm[s], yt);
    }
    float zz = z[bt*DI + d];
    y[bt*DI + d] = f2bf((yt + uu*Dd) * silu_f(zz));
  }
}

// ---------------- mean-pool partials over T (bf16 input) ----------------
__global__ __launch_bounds__(256)
void k_poolpart(const unsigned short* __restrict__ hn, float* __restrict__ pp) {
  int seg = blockIdx.x, b = blockIdx.z;
  int d = blockIdx.y*256 + threadIdx.x;
  int t0 = seg*132, t1 = min(t0 + 132, TT);
  float s = 0.0f;
  for (int t = t0; t < t1; ++t) s += bf2f(hn[((size_t)b*TT + t)*DM + d]);
  pp[((size_t)b*32 + seg)*DM + d] = s;
}

// ---------------- final head ----------------
__global__ __launch_bounds__(256)
void k_head(const float* __restrict__ pp, const float* __restrict__ pw,
            const float* __restrict__ pb, const float* __restrict__ lnw,
            const float* __restrict__ lnb, float* __restrict__ out) {
  int b = blockIdx.x, tid = threadIdx.x;
  __shared__ float pooled[DM];
  for (int d = tid; d < DM; d += 256) {
    float s = 0.0f;
    for (int seg = 0; seg < 32; ++seg) s += pp[((size_t)b*32 + seg)*DM + d];
    pooled[d] = s * (1.0f/(float)TT);
  }
  __syncthreads();
  __shared__ float zed[64];
  if (tid < 64) {
    float s = pb[tid];
    const float* w = pw + (size_t)tid*DM;
    for (int d = 0; d < DM; ++d) s = fmaf(pooled[d], w[d], s);
    zed[tid] = s;
  }
  __syncthreads();
  __shared__ float mv[2];
  if (tid == 0) {
    float mu = 0.0f;
    for (int l = 0; l < 64; ++l) mu += zed[l];
    mu *= (1.0f/64.0f);
    float var = 0.0f;
    for (int l = 0; l < 64; ++l) { float dd = zed[l]-mu; var += dd*dd; }
    var *= (1.0f/64.0f);
    mv[0] = mu; mv[1] = rsqrtf(var + 1e-5f);
  }
  __syncthreads();
  if (tid < 64) out[b*64 + tid] = (zed[tid]-mv[0])*mv[1]*lnw[tid] + lnb[tid];
}

extern "C" void kernel_launch(void* const* d_in, const int* in_sizes, int n_in,
                              void* d_out, int out_size, void* d_ws, size_t ws_size,
                              hipStream_t stream) {
  (void)in_sizes; (void)n_in; (void)out_size; (void)ws_size;
  const float* x    = (const float*)d_in[0];
  const float* cw   = (const float*)d_in[1];
  const float* cb   = (const float*)d_in[2];
  const float* nw   = (const float*)d_in[3];
  const float* inw  = (const float*)d_in[4];
  const float* c1w  = (const float*)d_in[5];
  const float* c1b  = (const float*)d_in[6];
  const float* xpw  = (const float*)d_in[7];
  const float* dtw  = (const float*)d_in[8];
  const float* dtb  = (const float*)d_in[9];
  const float* alog = (const float*)d_in[10];
  const float* dsk  = (const float*)d_in[11];
  const float* outw = (const float*)d_in[12];
  const float* nfw  = (const float*)d_in[13];
  const float* pw   = (const float*)d_in[14];
  const float* pb   = (const float*)d_in[15];
  const float* lnw  = (const float*)d_in[16];
  const float* lnb  = (const float*)d_in[17];

  char* wsb = (char*)d_ws;
  size_t o = 0;
  float* f_h  = (float*)(wsb + o); o += (size_t)ROWS*DM*4;
  float* f_u0 = (float*)(wsb + o); o += (size_t)ROWS*DI*4;   // pre-conv u (fp32)
  float* f_z  = (float*)(wsb + o); o += (size_t)ROWS*DI*4;
  float* f_u  = (float*)(wsb + o); o += (size_t)ROWS*DI*4;   // post-conv u (fp32)
  float* f_pr = (float*)(wsb + o); o += (size_t)ROWS*80*4;
  float* f_dl = (float*)(wsb + o); o += (size_t)ROWS*DI*4;
  float* f_P  = (float*)(wsb + o); o += (size_t)NCHUNK*BB*DI*DS*4;
  float* f_H  = (float*)(wsb + o); o += (size_t)NCHUNK*BB*DI*DS*4;
  float* f_pp = (float*)(wsb + o); o += (size_t)BB*32*DM*4;
  unsigned short* hn_bf = (unsigned short*)(wsb + o); o += (size_t)ROWS*DM*2;
  unsigned short* u_bf  = (unsigned short*)(wsb + o); o += (size_t)ROWS*DI*2;
  unsigned short* y_bf  = (unsigned short*)(wsb + o); o += (size_t)ROWS*DI*2;
  unsigned short* w_in  = (unsigned short*)(wsb + o); o += (size_t)2*DI*DM*2;
  unsigned short* w_xp  = (unsigned short*)(wsb + o); o += (size_t)80*DI*2;
  unsigned short* w_out = (unsigned short*)(wsb + o); o += (size_t)DM*DI*2;

  k_conv_ds<<<ROWS, 256, 0, stream>>>(x, cw, cb, f_h);

  for (int lay = 0; lay < NLAYER; ++lay) {
    // weight converts for this layer
    k_f2bf<<<(2*DI*DM/4+255)/256, 256, 0, stream>>>(
        (const float4*)(inw + (size_t)lay*2*DI*DM), (ushort4*)w_in, 2*DI*DM/4);
    k_f2bf<<<(80*DI/4+255)/256, 256, 0, stream>>>(
        (const float4*)(xpw + (size_t)lay*80*DI), (ushort4*)w_xp, 80*DI/4);
    k_f2bf<<<(DM*DI/4+255)/256, 256, 0, stream>>>(
        (const float4*)(outw + (size_t)lay*DM*DI), (ushort4*)w_out, DM*DI/4);

    k_rmsnorm<<<ROWS, 256, 0, stream>>>(f_h, nw + (size_t)lay*DM, hn_bf);
    k_gemm_bf<true,false><<<dim3(66,24), 256, 0, stream>>>(
        hn_bf, w_in, f_u0, f_z, DI, ROWS, 2*DI, DM);
    k_dwconv<<<(ROWS*DI+255)/256, 256, 0, stream>>>(
        f_u0, c1w + (size_t)lay*DI*4, c1b + (size_t)lay*DI, f_u, u_bf);
    k_gemm_bf<false,false><<<dim3(66,1), 256, 0, stream>>>(
        u_bf, w_xp, f_pr, nullptr, 80, ROWS, 80, DI);
    k_gemm<1><<<dim3(66,12), 256, 0, stream>>>(
        f_pr, 80, dtw + (size_t)lay*DI*DTR, dtb + (size_t)lay*DI,
        f_dl, DI, ROWS, DI, DTR);
    k_scan1<<<dim3(NCHUNK,6,BB), 256, 0, stream>>>(
        f_dl, f_u, f_pr, alog + (size_t)lay*DI*DS, f_P, f_H);
    k_scan2<<<dim3((BB*DI*DS)/256), 256, 0, stream>>>(f_P, f_H);
    k_scan3<<<dim3(NCHUNK,6,BB), 256, 0, stream>>>(
        f_dl, f_u, f_z, f_pr, alog + (size_t)lay*DI*DS,
        dsk + (size_t)lay*DI, f_H, y_bf);
    k_gemm_bf<false,true><<<dim3(66,6), 256, 0, stream>>>(
        y_bf, w_out, f_h, nullptr, DM, ROWS, DM, DI);
  }

  k_rmsnorm<<<ROWS, 256, 0, stream>>>(f_h, nfw, hn_bf);
  k_poolpart<<<dim3(32,3,BB), 256, 0, stream>>>(hn_bf, f_pp);
  k_head<<<BB, 256, 0, stream>>>(f_pp, pw, pb, lnw, lnb, (float*)d_out);
}

// Round 3
// 10996.096 us; speedup vs baseline: 3.3887x; 1.2748x over previous
//
#include <hip/hip_runtime.h>
#include <hip/hip_bf16.h>
#include <math.h>

#define TT 4218
#define BB 2
#define DM 768
#define DI 1536
#define DS 16
#define DTR 48
#define LC 64
#define NCHUNK 66
#define ROWS (BB*TT)   // 8436
#define NLAYER 24

typedef short short8 __attribute__((ext_vector_type(8)));
typedef float f32x4 __attribute__((ext_vector_type(4)));

__device__ __forceinline__ float silu_f(float x) { return x / (1.0f + __expf(-x)); }
__device__ __forceinline__ float softplus_f(float x) {
  return (x > 15.0f) ? x : log1pf(__expf(x));
}
__device__ __forceinline__ unsigned short f2bf(float x) {  // RNE
  unsigned int u = __float_as_uint(x);
  u = (u + 0x7fffu + ((u >> 16) & 1u)) >> 16;
  return (unsigned short)u;
}
__device__ __forceinline__ float bf2f(unsigned short s) {
  return __uint_as_float(((unsigned int)s) << 16);
}

// ---------------- fp32 -> bf16 bulk convert ----------------
__global__ __launch_bounds__(256)
void k_f2bf(const float4* __restrict__ in, ushort4* __restrict__ out, int n4) {
  int i = blockIdx.x*256 + threadIdx.x;
  if (i >= n4) return;
  float4 v = in[i];
  ushort4 o;
  o.x = f2bf(v.x); o.y = f2bf(v.y); o.z = f2bf(v.z); o.w = f2bf(v.w);
  out[i] = o;
}

// dt_proj weights: (NL,1536,48) fp32 -> (NL,1536,64) bf16, pad cols 48..63 = 0
__global__ __launch_bounds__(256)
void k_cvt_dtw(const float* __restrict__ in, unsigned short* __restrict__ out, int n) {
  int i = blockIdx.x*256 + threadIdx.x;
  if (i >= n) return;
  int col = i & 63, row = i >> 6;
  out[i] = (col < DTR) ? f2bf(in[row*DTR + col]) : (unsigned short)0;
}

// zero pad cols 48..63 of f_dt (stays zero across all layers within a call)
__global__ __launch_bounds__(256)
void k_zero_dtpad(unsigned short* __restrict__ fdt) {
  int i = blockIdx.x*256 + threadIdx.x;
  if (i >= ROWS*16) return;
  int r = i >> 4, c = i & 15;
  fdt[(size_t)r*64 + DTR + c] = 0;
}

// ---------------- downsample conv: x (B,1,135000) -> h (B,T,768) ----------------
__global__ __launch_bounds__(256)
void k_conv_ds(const float* __restrict__ x, const float* __restrict__ cw,
               const float* __restrict__ cb, float* __restrict__ h) {
  int bt = blockIdx.x;
  int b = bt / TT, t = bt % TT;
  __shared__ float xs[32];
  int tid = threadIdx.x;
  if (tid < 32) xs[tid] = x[(size_t)b*135000 + (size_t)t*32 + tid];
  __syncthreads();
  for (int d = tid; d < DM; d += 256) {
    float s = cb[d];
    const float* w = cw + d*32;
    #pragma unroll
    for (int k = 0; k < 32; ++k) s = fmaf(xs[k], w[k], s);
    h[(size_t)bt*DM + d] = s;
  }
}

// ---------------- RMSNorm over last dim (768), bf16 output ----------------
__global__ __launch_bounds__(256)
void k_rmsnorm(const float* __restrict__ in, const float* __restrict__ w,
               unsigned short* __restrict__ out) {
  int row = blockIdx.x, tid = threadIdx.x;
  const float* xp = in + (size_t)row*DM;
  float v0 = xp[tid], v1 = xp[tid+256], v2 = xp[tid+512];
  float ss = v0*v0 + v1*v1 + v2*v2;
  #pragma unroll
  for (int off = 32; off > 0; off >>= 1) ss += __shfl_down(ss, off, 64);
  __shared__ float sred[4];
  if ((tid & 63) == 0) sred[tid >> 6] = ss;
  __syncthreads();
  float tot = sred[0] + sred[1] + sred[2] + sred[3];
  float sc = rsqrtf(tot * (1.0f/DM) + 1e-5f);
  unsigned short* op = out + (size_t)row*DM;
  op[tid]     = f2bf(v0*sc*w[tid]);
  op[tid+256] = f2bf(v1*sc*w[tid+256]);
  op[tid+512] = f2bf(v2*sc*w[tid+512]);
}

// ---------------- bf16 MFMA GEMM: C[M,N] = A[M,K] * W[N,K]^T ----------------
// 128x128 tile, BK=32, 4 waves of 64x64, 16x16x32 MFMA, global_load_lds staging
// with XOR-swizzled LDS. MODE 0: bf16 split store (u0/z); 1: fp32 accum;
// 2: fp32 store softplus(v + bias[col]).
#define GLL(g, l) __builtin_amdgcn_global_load_lds( \
    (const __attribute__((address_space(1))) void*)(g), \
    (__attribute__((address_space(3))) void*)(l), 16, 0, 0)

template<int MODE>
__global__ __launch_bounds__(256)
void k_gemm_bf(const unsigned short* __restrict__ A,
               const unsigned short* __restrict__ W,
               const float* __restrict__ bias,
               float* __restrict__ Cf,
               unsigned short* __restrict__ Cb0, unsigned short* __restrict__ Cb1,
               int ldc, int M, int N, int K) {
  __shared__ unsigned short As[128*32];
  __shared__ unsigned short Ws[128*32];
  const int tid = threadIdx.x;
  const int m0 = blockIdx.x*128, n0 = blockIdx.y*128;
  const int lane = tid & 63;
  const int wave = tid >> 6;
  const int wm = (wave >> 1)*64, wn = (wave & 1)*64;

  const int sA = tid & 3;
  const int r0 = tid >> 2;
  const int r1 = r0 + 64;
  const int seg0 = sA ^ ((r0 >> 1) & 3);
  const int seg1 = sA ^ ((r1 >> 1) & 3);
  const unsigned short* gA0 = A + (size_t)min(m0+r0, M-1)*K + seg0*8;
  const unsigned short* gA1 = A + (size_t)min(m0+r1, M-1)*K + seg1*8;
  const unsigned short* gW0 = W + (size_t)min(n0+r0, N-1)*K + seg0*8;
  const unsigned short* gW1 = W + (size_t)min(n0+r1, N-1)*K + seg1*8;
  unsigned short* lA0 = As + tid*8;
  unsigned short* lA1 = As + (tid+256)*8;
  unsigned short* lW0 = Ws + tid*8;
  unsigned short* lW1 = Ws + (tid+256)*8;

  f32x4 acc[4][4];
  #pragma unroll
  for (int i = 0; i < 4; ++i)
    #pragma unroll
    for (int j = 0; j < 4; ++j) acc[i][j] = (f32x4){0.f,0.f,0.f,0.f};

  const int lr = lane & 15, kg = lane >> 4;
  const int sw = (kg ^ ((lr >> 1) & 3)) * 8;
  const int aoff = (wm + lr)*32 + sw;
  const int boff = (wn + lr)*32 + sw;

  for (int k0 = 0; k0 < K; k0 += 32) {
    GLL(gA0, lA0); GLL(gA1, lA1);
    GLL(gW0, lW0); GLL(gW1, lW1);
    gA0 += 32; gA1 += 32; gW0 += 32; gW1 += 32;
    __syncthreads();
    short8 af[4], bfr[4];
    #pragma unroll
    for (int i = 0; i < 4; ++i) {
      af[i]  = *(const short8*)(As + aoff + i*512);
      bfr[i] = *(const short8*)(Ws + boff + i*512);
    }
    #pragma unroll
    for (int i = 0; i < 4; ++i)
      #pragma unroll
      for (int j = 0; j < 4; ++j)
        acc[i][j] = __builtin_amdgcn_mfma_f32_16x16x32_bf16(af[i], bfr[j], acc[i][j], 0, 0, 0);
    __syncthreads();
  }

  // C/D layout: col=lane&15, row=(lane>>4)*4+reg
  #pragma unroll
  for (int i = 0; i < 4; ++i) {
    int gr0 = m0 + wm + i*16 + kg*4;
    #pragma unroll
    for (int j = 0; j < 4; ++j) {
      int gc = n0 + wn + j*16 + lr;
      if (gc >= N) continue;
      #pragma unroll
      for (int r = 0; r < 4; ++r) {
        int gr = gr0 + r;
        if (gr >= M) continue;
        float v = acc[i][j][r];
        if (MODE == 0) {
          if (gc < DI) Cb0[(size_t)gr*ldc + gc] = f2bf(v);
          else         Cb1[(size_t)gr*ldc + gc - DI] = f2bf(v);
        } else if (MODE == 1) {
          Cf[(size_t)gr*ldc + gc] += v;
        } else {
          Cf[(size_t)gr*ldc + gc] = softplus_f(v + bias[gc]);
        }
      }
    }
  }
}

// ---------------- x_proj GEMM: C[M,80] = A[M,1536] * W[80,1536]^T ----------------
// M-tile 64 (132 blocks), 4 waves x 16 rows x 80 cols. Emits fp32 f_pr and
// bf16 f_dt (cols<48, row stride 64) for the dt_proj MFMA GEMM.
__global__ __launch_bounds__(256)
void k_gemm_xp(const unsigned short* __restrict__ A,
               const unsigned short* __restrict__ W,
               float* __restrict__ Cpr, unsigned short* __restrict__ Cdt,
               int M) {
  __shared__ unsigned short As[64*32];
  __shared__ unsigned short Ws[80*32];
  const int tid = threadIdx.x;
  const int m0 = blockIdx.x*64;
  const int lane = tid & 63;
  const int wave = tid >> 6;
  const int K = DI;

  // A staging: 256 chunks of 16B
  const int rA = tid >> 2;
  const int segA = (tid & 3) ^ ((rA >> 1) & 3);
  const unsigned short* gA = A + (size_t)min(m0+rA, M-1)*K + segA*8;
  unsigned short* lA = As + tid*8;
  // W staging: 320 chunks; threads 0..255 + wave0 extra 64
  const int rW0 = tid >> 2;
  const int segW0 = (tid & 3) ^ ((rW0 >> 1) & 3);
  const unsigned short* gW0 = W + (size_t)rW0*K + segW0*8;
  unsigned short* lW0 = Ws + tid*8;
  const int idx1 = tid + 256;
  const int rW1 = idx1 >> 2;
  const int segW1 = (idx1 & 3) ^ ((rW1 >> 1) & 3);
  const unsigned short* gW1 = W + (size_t)min(rW1,79)*K + segW1*8;
  unsigned short* lW1 = Ws + (size_t)idx1*8;

  f32x4 acc[5];
  #pragma unroll
  for (int j = 0; j < 5; ++j) acc[j] = (f32x4){0.f,0.f,0.f,0.f};

  const int lr = lane & 15, kg = lane >> 4;
  const int sw = (kg ^ ((lr >> 1) & 3)) * 8;
  const int aoff = (wave*16 + lr)*32 + sw;

  for (int k0 = 0; k0 < K; k0 += 32) {
    GLL(gA, lA);
    GLL(gW0, lW0);
    if (wave == 0) GLL(gW1, lW1);
    gA += 32; gW0 += 32; gW1 += 32;
    __syncthreads();
    short8 af = *(const short8*)(As + aoff);
    #pragma unroll
    for (int j = 0; j < 5; ++j) {
      short8 bf = *(const short8*)(Ws + (j*16 + lr)*32 + sw);
      acc[j] = __builtin_amdgcn_mfma_f32_16x16x32_bf16(af, bf, acc[j], 0, 0, 0);
    }
    __syncthreads();
  }

  #pragma unroll
  for (int j = 0; j < 5; ++j) {
    int gc = j*16 + lr;
    #pragma unroll
    for (int r = 0; r < 4; ++r) {
      int gr = m0 + wave*16 + kg*4 + r;
      if (gr >= M) continue;
      float v = acc[j][r];
      Cpr[(size_t)gr*80 + gc] = v;
      if (gc < DTR) Cdt[(size_t)gr*64 + gc] = f2bf(v);
    }
  }
}

// ---------------- causal depthwise conv (k=4) + silu; bf16 in/out ----------------
__global__ __launch_bounds__(256)
void k_dwconv(const unsigned short* __restrict__ U0, const float* __restrict__ cw,
              const float* __restrict__ cb, unsigned short* __restrict__ ubf) {
  size_t i = (size_t)blockIdx.x*256 + threadIdx.x;
  if (i >= (size_t)ROWS*DI) return;
  int d = (int)(i % DI);
  long bt = (long)(i / DI);
  int t = (int)(bt % TT);
  float s = cb[d];
  #pragma unroll
  for (int k = 0; k < 4; ++k) {
    int tt = t - 3 + k;
    if (tt >= 0) s = fmaf(bf2f(U0[(size_t)(bt - 3 + k)*DI + d]), cw[d*4 + k], s);
  }
  ubf[i] = f2bf(silu_f(s));
}

// ---------------- selective scan, 3-pass chunked linear recurrence ----------------
__global__ __launch_bounds__(256)
void k_scan1(const float* __restrict__ delta, const unsigned short* __restrict__ u,
             const float* __restrict__ proj, const float* __restrict__ A_log,
             float* __restrict__ P, float* __restrict__ H) {
  int c = blockIdx.x, b = blockIdx.z;
  int d = blockIdx.y * 256 + threadIdx.x;
  float A[DS];
  #pragma unroll
  for (int s = 0; s < DS; ++s) A[s] = -__expf(A_log[d*DS + s]);
  float h[DS] = {};
  float Pp[DS];
  #pragma unroll
  for (int s = 0; s < DS; ++s) Pp[s] = 1.0f;
  int t0 = c * LC, t1 = min(t0 + LC, TT);
  for (int t = t0; t < t1; ++t) {
    size_t bt = (size_t)b*TT + t;
    float dl = delta[bt*DI + d];
    float du = dl * bf2f(u[bt*DI + d]);
    const float* pbm = proj + bt*80 + DTR;
    #pragma unroll
    for (int s = 0; s < DS; ++s) {
      float e = __expf(dl * A[s]);
      Pp[s] *= e;
      h[s] = fmaf(e, h[s], du * pbm[s]);
    }
  }
  size_t o = (((size_t)c*BB + b)*DI + d)*DS;
  #pragma unroll
  for (int s = 0; s < DS; ++s) { P[o+s] = Pp[s]; H[o+s] = h[s]; }
}

__global__ __launch_bounds__(256)
void k_scan2(float* __restrict__ P, float* __restrict__ H) {
  int i = blockIdx.x*256 + threadIdx.x;
  const int CH = BB*DI*DS;
  float carry = 0.0f;
  for (int c = 0; c < NCHUNK; ++c) {
    size_t o = (size_t)c*CH + i;
    float p = P[o], h0 = H[o];
    H[o] = carry;
    carry = fmaf(p, carry, h0);
  }
}

__global__ __launch_bounds__(256)
void k_scan3(const float* __restrict__ delta, const unsigned short* __restrict__ u,
             const unsigned short* __restrict__ z, const float* __restrict__ proj,
             const float* __restrict__ A_log, const float* __restrict__ Dskip,
             const float* __restrict__ H, unsigned short* __restrict__ y) {
  int c = blockIdx.x, b = blockIdx.z;
  int d = blockIdx.y * 256 + threadIdx.x;
  float A[DS];
  #pragma unroll
  for (int s = 0; s < DS; ++s) A[s] = -__expf(A_log[d*DS + s]);
  float h[DS];
  size_t o = (((size_t)c*BB + b)*DI + d)*DS;
  #pragma unroll
  for (int s = 0; s < DS; ++s) h[s] = H[o+s];
  float Dd = Dskip[d];
  int t0 = c * LC, t1 = min(t0 + LC, TT);
  for (int t = t0; t < t1; ++t) {
    size_t bt = (size_t)b*TT + t;
    float dl = delta[bt*DI + d];
    float uu = bf2f(u[bt*DI + d]);
    float du = dl * uu;
    const float* pbm = proj + bt*80 + DTR;
    const float* pcm = pbm + DS;
    float yt = 0.0f;
    #pragma unroll
    for (int s = 0; s < DS; ++s) {
      float e = __expf(dl * A[s]);
      h[s] = fmaf(e, h[s], du * pbm[s]);
      yt = fmaf(h[s], pcm[s], yt);
    }
    float zz = bf2f(z[bt*DI + d]);
    y[bt*DI + d] = f2bf((yt + uu*Dd) * silu_f(zz));
  }
}

// ---------------- mean-pool partials over T (bf16 input) ----------------
__global__ __launch_bounds__(256)
void k_poolpart(const unsigned short* __restrict__ hn, float* __restrict__ pp) {
  int seg = blockIdx.x, b = blockIdx.z;
  int d = blockIdx.y*256 + threadIdx.x;
  int t0 = seg*132, t1 = min(t0 + 132, TT);
  float s = 0.0f;
  for (int t = t0; t < t1; ++t) s += bf2f(hn[((size_t)b*TT + t)*DM + d]);
  pp[((size_t)b*32 + seg)*DM + d] = s;
}

// ---------------- final head ----------------
__global__ __launch_bounds__(256)
void k_head(const float* __restrict__ pp, const float* __restrict__ pw,
            const float* __restrict__ pb, const float* __restrict__ lnw,
            const float* __restrict__ lnb, float* __restrict__ out) {
  int b = blockIdx.x, tid = threadIdx.x;
  __shared__ float pooled[DM];
  for (int d = tid; d < DM; d += 256) {
    float s = 0.0f;
    for (int seg = 0; seg < 32; ++seg) s += pp[((size_t)b*32 + seg)*DM + d];
    pooled[d] = s * (1.0f/(float)TT);
  }
  __syncthreads();
  __shared__ float zed[64];
  if (tid < 64) {
    float s = pb[tid];
    const float* w = pw + (size_t)tid*DM;
    for (int d = 0; d < DM; ++d) s = fmaf(pooled[d], w[d], s);
    zed[tid] = s;
  }
  __syncthreads();
  __shared__ float mv[2];
  if (tid == 0) {
    float mu = 0.0f;
    for (int l = 0; l < 64; ++l) mu += zed[l];
    mu *= (1.0f/64.0f);
    float var = 0.0f;
    for (int l = 0; l < 64; ++l) { float dd = zed[l]-mu; var += dd*dd; }
    var *= (1.0f/64.0f);
    mv[0] = mu; mv[1] = rsqrtf(var + 1e-5f);
  }
  __syncthreads();
  if (tid < 64) out[b*64 + tid] = (zed[tid]-mv[0])*mv[1]*lnw[tid] + lnb[tid];
}

extern "C" void kernel_launch(void* const* d_in, const int* in_sizes, int n_in,
                              void* d_out, int out_size, void* d_ws, size_t ws_size,
                              hipStream_t stream) {
  (void)in_sizes; (void)n_in; (void)out_size; (void)ws_size;
  const float* x    = (const float*)d_in[0];
  const float* cw   = (const float*)d_in[1];
  const float* cb   = (const float*)d_in[2];
  const float* nw   = (const float*)d_in[3];
  const float* inw  = (const float*)d_in[4];
  const float* c1w  = (const float*)d_in[5];
  const float* c1b  = (const float*)d_in[6];
  const float* xpw  = (const float*)d_in[7];
  const float* dtw  = (const float*)d_in[8];
  const float* dtb  = (const float*)d_in[9];
  const float* alog = (const float*)d_in[10];
  const float* dsk  = (const float*)d_in[11];
  const float* outw = (const float*)d_in[12];
  const float* nfw  = (const float*)d_in[13];
  const float* pw   = (const float*)d_in[14];
  const float* pb   = (const float*)d_in[15];
  const float* lnw  = (const float*)d_in[16];
  const float* lnb  = (const float*)d_in[17];

  char* wsb = (char*)d_ws;
  size_t o = 0;
  float* f_h  = (float*)(wsb + o); o += (size_t)ROWS*DM*4;
  float* f_pr = (float*)(wsb + o); o += (size_t)ROWS*80*4;
  float* f_dl = (float*)(wsb + o); o += (size_t)ROWS*DI*4;
  float* f_P  = (float*)(wsb + o); o += (size_t)NCHUNK*BB*DI*DS*4;
  float* f_H  = (float*)(wsb + o); o += (size_t)NCHUNK*BB*DI*DS*4;
  float* f_pp = (float*)(wsb + o); o += (size_t)BB*32*DM*4;
  unsigned short* hn_bf = (unsigned short*)(wsb + o); o += (size_t)ROWS*DM*2;
  unsigned short* u0_bf = (unsigned short*)(wsb + o); o += (size_t)ROWS*DI*2;
  unsigned short* z_bf  = (unsigned short*)(wsb + o); o += (size_t)ROWS*DI*2;
  unsigned short* u_bf  = (unsigned short*)(wsb + o); o += (size_t)ROWS*DI*2;
  unsigned short* y_bf  = (unsigned short*)(wsb + o); o += (size_t)ROWS*DI*2;
  unsigned short* f_dt  = (unsigned short*)(wsb + o); o += (size_t)ROWS*64*2;
  unsigned short* w_in  = (unsigned short*)(wsb + o); o += (size_t)2*DI*DM*2;
  unsigned short* w_xp  = (unsigned short*)(wsb + o); o += (size_t)NLAYER*80*DI*2;
  unsigned short* w_out = (unsigned short*)(wsb + o); o += (size_t)NLAYER*DM*DI*2;
  unsigned short* w_dt  = (unsigned short*)(wsb + o); o += (size_t)NLAYER*DI*64*2;

  k_conv_ds<<<ROWS, 256, 0, stream>>>(x, cw, cb, f_h);
  // hoisted weight conversions (all layers)
  k_f2bf<<<(NLAYER*80*DI/4+255)/256, 256, 0, stream>>>(
      (const float4*)xpw, (ushort4*)w_xp, NLAYER*80*DI/4);
  k_f2bf<<<(NLAYER*DM*DI/4+255)/256, 256, 0, stream>>>(
      (const float4*)outw, (ushort4*)w_out, NLAYER*DM*DI/4);
  k_cvt_dtw<<<(NLAYER*DI*64+255)/256, 256, 0, stream>>>(dtw, w_dt, NLAYER*DI*64);
  k_zero_dtpad<<<(ROWS*16+255)/256, 256, 0, stream>>>(f_dt);

  for (int lay = 0; lay < NLAYER; ++lay) {
    k_f2bf<<<(2*DI*DM/4+255)/256, 256, 0, stream>>>(
        (const float4*)(inw + (size_t)lay*2*DI*DM), (ushort4*)w_in, 2*DI*DM/4);
    k_rmsnorm<<<ROWS, 256, 0, stream>>>(f_h, nw + (size_t)lay*DM, hn_bf);
    k_gemm_bf<0><<<dim3(66,24), 256, 0, stream>>>(
        hn_bf, w_in, nullptr, nullptr, u0_bf, z_bf, DI, ROWS, 2*DI, DM);
    k_dwconv<<<((size_t)ROWS*DI+255)/256, 256, 0, stream>>>(
        u0_bf, c1w + (size_t)lay*DI*4, c1b + (size_t)lay*DI, u_bf);
    k_gemm_xp<<<132, 256, 0, stream>>>(
        u_bf, w_xp + (size_t)lay*80*DI, f_pr, f_dt, ROWS);
    k_gemm_bf<2><<<dim3(66,12), 256, 0, stream>>>(
        f_dt, w_dt + (size_t)lay*DI*64, dtb + (size_t)lay*DI,
        f_dl, nullptr, nullptr, DI, ROWS, DI, 64);
    k_scan1<<<dim3(NCHUNK,6,BB), 256, 0, stream>>>(
        f_dl, u_bf, f_pr, alog + (size_t)lay*DI*DS, f_P, f_H);
    k_scan2<<<dim3((BB*DI*DS)/256), 256, 0, stream>>>(f_P, f_H);
    k_scan3<<<dim3(NCHUNK,6,BB), 256, 0, stream>>>(
        f_dl, u_bf, z_bf, f_pr, alog + (size_t)lay*DI*DS,
        dsk + (size_t)lay*DI, f_H, y_bf);
    k_gemm_bf<1><<<dim3(66,6), 256, 0, stream>>>(
        y_bf, w_out + (size_t)lay*DM*DI, nullptr,
        f_h, nullptr, nullptr, DM, ROWS, DM, DI);
  }

  k_rmsnorm<<<ROWS, 256, 0, stream>>>(f_h, nfw, hn_bf);
  k_poolpart<<<dim3(32,3,BB), 256, 0, stream>>>(hn_bf, f_pp);
  k_head<<<BB, 256, 0, stream>>>(f_pp, pw, pb, lnw, lnb, (float*)d_out);
}